// Round 7
// baseline (210.789 us; speedup 1.0000x reference)
//
#include <hip/hip_runtime.h>
#include <hip/hip_fp16.h>

#define NF 128     // feature dim, fixed by the problem
#define DMAX 64    // fixed CSR stride (Poisson(16): P(deg>64) ~ 0; exact via ovf)

typedef _Float16 half8  __attribute__((ext_vector_type(8)));
typedef _Float16 half4v __attribute__((ext_vector_type(4)));
typedef float    floatx4 __attribute__((ext_vector_type(4)));

// ---------------- z_k: zero cnt[0..N] + W1/W2 transpose->fp16 -------------------
__global__ __launch_bounds__(256) void z_k(
    int* __restrict__ cnt, int N, int zb,
    const float* __restrict__ W1, const float* __restrict__ W2,
    __half* __restrict__ WT1, __half* __restrict__ WT2)
{
    int b = blockIdx.x;
    if (b < zb) {
        int i = b * 256 + threadIdx.x;
        if (i <= N) cnt[i] = 0;            // cnt[N] = overflow counter
        return;
    }
    int idx = (b - zb) * 256 + threadIdx.x;   // 0..32767
    const float* W = (idx < 16384) ? W1 : W2;
    __half* WT     = (idx < 16384) ? WT1 : WT2;
    int j = idx & 16383;
    int nn = j & 127, k = j >> 7;
    WT[nn * NF + k] = __float2half(W[k * NF + nn]);
}

// ---------------- fill_k: single-pass CSR build via global atomics --------------
// pos = atomicAdd(cnt[d]); slots <DMAX go to csrF[d*DMAX+pos]; rest to exact
// overflow list (empty in practice). cnt ends as the true degree (for dinv).
__device__ __forceinline__ void fill_one(
    int d, int s, int* __restrict__ cnt, int* __restrict__ csrF,
    int* __restrict__ ovf, int N)
{
    int pos = atomicAdd(&cnt[d], 1);
    if (pos < DMAX) {
        csrF[(size_t)d * DMAX + pos] = s;
    } else {
        int o = atomicAdd(&cnt[N], 1);
        ovf[2 * o] = d; ovf[2 * o + 1] = s;
    }
}

__global__ __launch_bounds__(256) void fill_k(
    const int* __restrict__ src, const int* __restrict__ dst,
    int* __restrict__ cnt, int* __restrict__ csrF, int* __restrict__ ovf,
    int E, int N)
{
    int i4 = (blockIdx.x * 256 + threadIdx.x) * 4;
    if (i4 + 3 < E) {
        int4 d = *(const int4*)(dst + i4);
        int4 s = *(const int4*)(src + i4);
        fill_one(d.x, s.x, cnt, csrF, ovf, N);
        fill_one(d.y, s.y, cnt, csrF, ovf, N);
        fill_one(d.z, s.z, cnt, csrF, ovf, N);
        fill_one(d.w, s.w, cnt, csrF, ovf, N);
    } else {
        for (int e = i4; e < E; e++)
            fill_one(dst[e], src[e], cnt, csrF, ovf, N);
    }
}

// ---------------- gemm1_k: H16 = fp16( (x @ W1) * dinv[row] ) -------------------
__global__ __launch_bounds__(512) void gemm1_k(
    const float* __restrict__ X, const __half* __restrict__ WT,
    const int* __restrict__ cnt, __half* __restrict__ H, int M)
{
    __shared__ __half wlds[128][136];
    const int tid = threadIdx.x;
    {   // stage WT (128x128 halves): 4 threads/row, 32 halves each
        int r = tid >> 2;
        int c0 = (tid & 3) * 32;
        const half8* s = (const half8*)(WT + (size_t)r * NF + c0);
        half8* d = (half8*)&wlds[r][c0];
        #pragma unroll
        for (int j = 0; j < 4; j++) d[j] = s[j];
    }
    __syncthreads();

    const int wave = tid >> 6, lane = tid & 63;
    const int quad = lane >> 4, l15 = lane & 15;
    const int rowA = blockIdx.x * 128 + wave * 16 + l15;
    const int rowc = (rowA < M) ? rowA : (M - 1);

    half8 afr[4];
    #pragma unroll
    for (int kc = 0; kc < 4; kc++) {
        const floatx4* p = (const floatx4*)(X + (size_t)rowc * NF + kc * 32 + quad * 8);
        floatx4 u = p[0], v = p[1];
        half8 a;
        a[0] = (_Float16)u[0]; a[1] = (_Float16)u[1];
        a[2] = (_Float16)u[2]; a[3] = (_Float16)u[3];
        a[4] = (_Float16)v[0]; a[5] = (_Float16)v[1];
        a[6] = (_Float16)v[2]; a[7] = (_Float16)v[3];
        afr[kc] = a;
    }

    floatx4 acc[8];
    #pragma unroll
    for (int ct = 0; ct < 8; ct++) { floatx4 z = {0.f, 0.f, 0.f, 0.f}; acc[ct] = z; }

    #pragma unroll
    for (int kc = 0; kc < 4; kc++) {
        #pragma unroll
        for (int ct = 0; ct < 8; ct++) {
            half8 b = *(const half8*)&wlds[ct * 16 + l15][kc * 32 + quad * 8];
            acc[ct] = __builtin_amdgcn_mfma_f32_16x16x32_f16(afr[kc], b, acc[ct], 0, 0, 0);
        }
    }

    const int orow0 = blockIdx.x * 128 + wave * 16 + quad * 4;
    #pragma unroll
    for (int r = 0; r < 4; r++) {
        int orow = orow0 + r;
        if (orow < M) {
            float dv = rsqrtf((float)cnt[orow] + 1.0f);
            #pragma unroll
            for (int ct = 0; ct < 8; ct++)
                H[(size_t)orow * NF + ct * 16 + l15] = __float2half(acc[ct][r] * dv);
        }
    }
}

// ---------------- gather2w: 2 nodes/wave, 16B/lane loads (R6 champion) ----------
// Fixed-stride csrF: base = node*DMAX, degree from cnt (capped DMAX; excess in
// ovf). Lane groups g=lane>>4: {0,1}=node A edge parity {0,1}; {2,3}=node B.
// fl=lane&15 covers features fl*8..fl*8+7. 8 loads (16B) back-to-back per batch.
__device__ __forceinline__ void gather2w(
    const half8* __restrict__ hs8, const int* __restrict__ csrF,
    const int* __restrict__ cnt, int nA, int n,
    int g, int fl, int lane, floatx4& ac0, floatx4& ac1,
    const int* __restrict__ ovf, int novf)
{
    const int ep  = g & 1;        // edge parity
    const int isB = g >> 1;       // which node this lane group serves
    const int nB  = nA + 1;

    int cntA = (nA < n) ? cnt[nA] : 0;
    int cntB = (nB < n) ? cnt[nB] : 0;
    const int ccA = min(cntA, DMAX), ccB = min(cntB, DMAX);

    int idxA = (lane < ccA) ? __builtin_nontemporal_load(&csrF[(size_t)nA * DMAX + lane]) : 0;
    int idxB = (lane < ccB) ? __builtin_nontemporal_load(&csrF[(size_t)nB * DMAX + lane]) : 0;

    // self-loops (parity-0 groups only; each group adds its own node's row)
    if (ep == 0) {
        int nd = isB ? nB : nA;
        if (nd < n) {
            half8 s = hs8[(size_t)nd * 16 + fl];
            ac0[0] += (float)s[0]; ac0[1] += (float)s[1];
            ac0[2] += (float)s[2]; ac0[3] += (float)s[3];
            ac1[0] += (float)s[4]; ac1[1] += (float)s[5];
            ac1[2] += (float)s[6]; ac1[3] += (float)s[7];
        }
    }

    const int myc  = isB ? ccB : ccA;
    const int maxc = max(ccA, ccB);
    for (int j = 0; j < maxc; j += 16) {   // 16 edges/node per batch, 8 loads deep
        int s[8];
        half8 v[8];
        #pragma unroll
        for (int t = 0; t < 8; t++) {
            int e = j + 2 * t + ep;
            int eA = min(e, ccA - 1); eA = (eA < 0) ? 0 : eA;
            int eB = min(e, ccB - 1); eB = (eB < 0) ? 0 : eB;
            int sa = __shfl(idxA, eA, 64);
            int sb = __shfl(idxB, eB, 64);
            s[t] = isB ? sb : sa;
        }
        #pragma unroll
        for (int t = 0; t < 8; t++)
            v[t] = hs8[(size_t)s[t] * 16 + fl];
        #pragma unroll
        for (int t = 0; t < 8; t++) {
            if (j + 2 * t + ep < myc) {
                ac0[0] += (float)v[t][0]; ac0[1] += (float)v[t][1];
                ac0[2] += (float)v[t][2]; ac0[3] += (float)v[t][3];
                ac1[0] += (float)v[t][4]; ac1[1] += (float)v[t][5];
                ac1[2] += (float)v[t][6]; ac1[3] += (float)v[t][7];
            }
        }
    }

    // exact-correctness overflow path (deg > DMAX) — empty in practice
    if (novf > 0 && ep == 0) {
        int myN = isB ? nB : nA;
        for (int i = 0; i < novf; i++) {
            int d = ovf[2 * i];
            if (d == myN) {
                half8 v = hs8[(size_t)ovf[2 * i + 1] * 16 + fl];
                ac0[0] += (float)v[0]; ac0[1] += (float)v[1];
                ac0[2] += (float)v[2]; ac0[3] += (float)v[3];
                ac1[0] += (float)v[4]; ac1[1] += (float)v[5];
                ac1[2] += (float)v[6]; ac1[3] += (float)v[7];
            }
        }
    }

    // combine parity halves: xor16 pairs g0<->g1 (node A) and g2<->g3 (node B)
    #pragma unroll
    for (int q = 0; q < 4; q++) {
        ac0[q] += __shfl_xor(ac0[q], 16, 64);
        ac1[q] += __shfl_xor(ac1[q], 16, 64);
    }
}

// ---------------- aggmm: fused agg(layer1) + gemm2; 512 thr, 16 nodes/block -----
__global__ __launch_bounds__(512) void aggmm_k(
    const __half* __restrict__ hs, const int* __restrict__ csrF,
    const int* __restrict__ cnt, const float* __restrict__ bias,
    const __half* __restrict__ WT, __half* __restrict__ Hout, int n,
    const int* __restrict__ ovf)
{
    __shared__ __half alds[16][136];
    const int tid = threadIdx.x;
    const int wave = tid >> 6, lane = tid & 63;
    const int g = lane >> 4, fl = lane & 15;
    const int nb0 = blockIdx.x * 16;
    const int nA = nb0 + wave * 2;
    const int novf = cnt[n];

    floatx4 ac0 = {0.f, 0.f, 0.f, 0.f}, ac1 = {0.f, 0.f, 0.f, 0.f};
    gather2w((const half8*)hs, csrF, cnt, nA, n, g, fl, lane, ac0, ac1, ovf, novf);

    if ((g & 1) == 0) {   // groups 0 (node A) and 2 (node B) write
        int node = nA + (g >> 1);
        int row  = wave * 2 + (g >> 1);
        half8 hv;
        if (node < n) {
            float dv = rsqrtf((float)cnt[node] + 1.0f);
            const floatx4 bv0 = *(const floatx4*)&bias[fl * 8];
            const floatx4 bv1 = *(const floatx4*)&bias[fl * 8 + 4];
            hv[0] = (_Float16)fmaxf(dv * ac0[0] + bv0[0], 0.f);
            hv[1] = (_Float16)fmaxf(dv * ac0[1] + bv0[1], 0.f);
            hv[2] = (_Float16)fmaxf(dv * ac0[2] + bv0[2], 0.f);
            hv[3] = (_Float16)fmaxf(dv * ac0[3] + bv0[3], 0.f);
            hv[4] = (_Float16)fmaxf(dv * ac1[0] + bv1[0], 0.f);
            hv[5] = (_Float16)fmaxf(dv * ac1[1] + bv1[1], 0.f);
            hv[6] = (_Float16)fmaxf(dv * ac1[2] + bv1[2], 0.f);
            hv[7] = (_Float16)fmaxf(dv * ac1[3] + bv1[3], 0.f);
        } else {
            #pragma unroll
            for (int i = 0; i < 8; i++) hv[i] = (_Float16)0.f;
        }
        *(half8*)&alds[row][fl * 8] = hv;
    }
    __syncthreads();

    // 16x128 output tile: wave w owns col-tile ct = w (16 cols)
    const int quad = lane >> 4, l15 = lane & 15;
    const int ct = wave;
    half8 afr[4];
    #pragma unroll
    for (int kc = 0; kc < 4; kc++)
        afr[kc] = *(const half8*)&alds[l15][kc * 32 + quad * 8];

    floatx4 o0 = {0.f, 0.f, 0.f, 0.f};
    #pragma unroll
    for (int kc = 0; kc < 4; kc++) {
        half8 b = *(const half8*)(WT + (size_t)(ct * 16 + l15) * NF + kc * 32 + quad * 8);
        o0 = __builtin_amdgcn_mfma_f32_16x16x32_f16(afr[kc], b, o0, 0, 0, 0);
    }

    #pragma unroll
    for (int r = 0; r < 4; r++) {
        int node = nb0 + quad * 4 + r;
        if (node < n) {
            float dv = rsqrtf((float)cnt[node] + 1.0f);
            Hout[(size_t)node * NF + ct * 16 + l15] = __float2half(o0[r] * dv);
        }
    }
}

// ---------------- agg4: final aggregate (fp32 out); 256 thr, 8 nodes/block ------
__global__ __launch_bounds__(256) void agg4_k(
    const __half* __restrict__ hs, const int* __restrict__ csrF,
    const int* __restrict__ cnt, const float* __restrict__ bias,
    float* __restrict__ outf, int n, const int* __restrict__ ovf)
{
    const int tid = threadIdx.x;
    const int wave = tid >> 6, lane = tid & 63;
    const int g = lane >> 4, fl = lane & 15;
    const int nA = blockIdx.x * 8 + wave * 2;
    if (nA >= n) return;
    const int novf = cnt[n];

    floatx4 ac0 = {0.f, 0.f, 0.f, 0.f}, ac1 = {0.f, 0.f, 0.f, 0.f};
    gather2w((const half8*)hs, csrF, cnt, nA, n, g, fl, lane, ac0, ac1, ovf, novf);

    if ((g & 1) == 0) {
        int node = nA + (g >> 1);
        if (node < n) {
            float dv = rsqrtf((float)cnt[node] + 1.0f);
            const floatx4 bv0 = *(const floatx4*)&bias[fl * 8];
            const floatx4 bv1 = *(const floatx4*)&bias[fl * 8 + 4];
            floatx4 w0, w1;
            w0[0] = dv * ac0[0] + bv0[0]; w0[1] = dv * ac0[1] + bv0[1];
            w0[2] = dv * ac0[2] + bv0[2]; w0[3] = dv * ac0[3] + bv0[3];
            w1[0] = dv * ac1[0] + bv1[0]; w1[1] = dv * ac1[1] + bv1[1];
            w1[2] = dv * ac1[2] + bv1[2]; w1[3] = dv * ac1[3] + bv1[3];
            *(floatx4*)(outf + (size_t)node * NF + fl * 8)     = w0;
            *(floatx4*)(outf + (size_t)node * NF + fl * 8 + 4) = w1;
        }
    }
}

// ---------------- launch ----------------

extern "C" void kernel_launch(void* const* d_in, const int* in_sizes, int n_in,
                              void* d_out, int out_size, void* d_ws, size_t ws_size,
                              hipStream_t stream) {
    const float* x  = (const float*)d_in[0];
    const int*   ei = (const int*)d_in[1];
    const float* W1 = (const float*)d_in[2];
    const float* b1 = (const float*)d_in[3];
    const float* W2 = (const float*)d_in[4];
    const float* b2 = (const float*)d_in[5];
    float* out = (float*)d_out;

    const int N = in_sizes[0] / NF;   // 50000
    const int E = in_sizes[1] / 2;    // 800000
    const int* src = ei;
    const int* dst = ei + E;

    char* ws = (char*)d_ws;
    size_t off = 0;
    auto alloc = [&](size_t bytes) {
        void* p = ws + off;
        off += bytes;
        off = (off + 63) & ~(size_t)63;
        return p;
    };
    int*    cnt  = (int*)alloc((size_t)(N + 1) * 4);        // degrees + ovf ctr
    int*    csrF = (int*)alloc((size_t)N * DMAX * 4);       // fixed-stride CSR
    int*    ovf  = (int*)alloc((size_t)E * 2 * 4);          // exact overflow list
    __half* WT1  = (__half*)alloc((size_t)NF * NF * 2);
    __half* WT2  = (__half*)alloc((size_t)NF * NF * 2);
    __half* H16  = (__half*)alloc((size_t)N * NF * 2);
    __half* A16  = (__half*)alloc((size_t)N * NF * 2);

    int zb = (N + 1 + 255) / 256;          // 196 zero-blocks
    int fbF = (E + 1023) / 1024;           // fill blocks (4 edges/thread)
    int GB  = (N + 127) / 128;             // gemm1 blocks (512 thr)
    int mb  = (N + 15) / 16;               // aggmm blocks (16 nodes, 512 thr)
    int ab  = (N + 7) / 8;                 // agg4 blocks (8 nodes, 256 thr)

    // zero degree counters + transpose W1/W2 to fp16
    z_k<<<zb + 128, 256, 0, stream>>>(cnt, N, zb, W1, W2, WT1, WT2);
    // single-pass CSR build (global atomics; no count/scan passes)
    fill_k<<<fbF, 256, 0, stream>>>(src, dst, cnt, csrF, ovf, E, N);
    // layer-1 GEMM with dinv prescale
    gemm1_k<<<GB, 512, 0, stream>>>(x, WT1, cnt, H16, N);
    // fused layer-1 aggregate + layer-2 GEMM
    aggmm_k<<<mb, 512, 0, stream>>>(H16, csrF, cnt, b1, WT2, A16, N, ovf);
    // final aggregate -> fp32 output
    agg4_k<<<ab, 256, 0, stream>>>(A16, csrF, cnt, b2, out, N, ovf);
}

// Round 8
// 209.673 us; speedup vs baseline: 1.0053x; 1.0053x over previous
//
#include <hip/hip_runtime.h>
#include <hip/hip_fp16.h>

#define NF 128     // feature dim, fixed by the problem
#define DMAX 64    // fixed CSR stride (Poisson(16): P(deg>64) ~ 0; exact via ovf)

typedef _Float16 half8  __attribute__((ext_vector_type(8)));
typedef _Float16 half4v __attribute__((ext_vector_type(4)));
typedef float    floatx4 __attribute__((ext_vector_type(4)));

// ---------------- z_k: zero cnt[0..N] + W1/W2 transpose->fp16 -------------------
__global__ __launch_bounds__(256) void z_k(
    int* __restrict__ cnt, int N, int zb,
    const float* __restrict__ W1, const float* __restrict__ W2,
    __half* __restrict__ WT1, __half* __restrict__ WT2)
{
    int b = blockIdx.x;
    if (b < zb) {
        int i = b * 256 + threadIdx.x;
        if (i <= N) cnt[i] = 0;            // cnt[N] = overflow counter
        return;
    }
    int idx = (b - zb) * 256 + threadIdx.x;   // 0..32767
    const float* W = (idx < 16384) ? W1 : W2;
    __half* WT     = (idx < 16384) ? WT1 : WT2;
    int j = idx & 16383;
    int nn = j & 127, k = j >> 7;
    WT[nn * NF + k] = __float2half(W[k * NF + nn]);
}

// ---------------- mix_k: co-dispatched {CSR fill} + {gemm1 raw} ------------------
// Fill (latency-bound: 1 atomic+store per thread, 800k threads) and gemm1
// (MFMA/BW-bound, writes UNSCALED fp32 H32 so it has no cnt dependency) are
// independent; interleaving 1 gemm block per 4 fill blocks co-resides both
// populations per CU so fill's memory-latency bubbles absorb gemm1's work.
__device__ __forceinline__ void gemm1raw_body(
    const float* __restrict__ X, const __half* __restrict__ WT,
    float* __restrict__ H32, int M, int bid, __half (*wlds)[136])
{
    const int tid = threadIdx.x;
    {   // stage WT (128x128 halves): 4 threads/row, 32 halves each
        int r = tid >> 2;
        int c0 = (tid & 3) * 32;
        const half8* s = (const half8*)(WT + (size_t)r * NF + c0);
        half8* d = (half8*)&wlds[r][c0];
        #pragma unroll
        for (int j = 0; j < 4; j++) d[j] = s[j];
    }
    __syncthreads();

    const int wave = tid >> 6, lane = tid & 63;
    const int quad = lane >> 4, l15 = lane & 15;
    const int rowA = bid * 128 + wave * 16 + l15;
    const int rowc = (rowA < M) ? rowA : (M - 1);

    half8 afr[4];
    #pragma unroll
    for (int kc = 0; kc < 4; kc++) {
        const floatx4* p = (const floatx4*)(X + (size_t)rowc * NF + kc * 32 + quad * 8);
        floatx4 u = p[0], v = p[1];
        half8 a;
        a[0] = (_Float16)u[0]; a[1] = (_Float16)u[1];
        a[2] = (_Float16)u[2]; a[3] = (_Float16)u[3];
        a[4] = (_Float16)v[0]; a[5] = (_Float16)v[1];
        a[6] = (_Float16)v[2]; a[7] = (_Float16)v[3];
        afr[kc] = a;
    }

    floatx4 acc[8];
    #pragma unroll
    for (int ct = 0; ct < 8; ct++) { floatx4 z = {0.f, 0.f, 0.f, 0.f}; acc[ct] = z; }

    #pragma unroll
    for (int kc = 0; kc < 4; kc++) {
        #pragma unroll
        for (int ct = 0; ct < 8; ct++) {
            half8 b = *(const half8*)&wlds[ct * 16 + l15][kc * 32 + quad * 8];
            acc[ct] = __builtin_amdgcn_mfma_f32_16x16x32_f16(afr[kc], b, acc[ct], 0, 0, 0);
        }
    }

    const int orow0 = bid * 128 + wave * 16 + quad * 4;
    #pragma unroll
    for (int r = 0; r < 4; r++) {
        int orow = orow0 + r;
        if (orow < M) {
            #pragma unroll
            for (int ct = 0; ct < 8; ct++)
                H32[(size_t)orow * NF + ct * 16 + l15] = acc[ct][r];
        }
    }
}

__global__ __launch_bounds__(512) void mix_k(
    const int* __restrict__ src, const int* __restrict__ dst,
    int* __restrict__ cnt, int* __restrict__ csrF, int* __restrict__ ovf,
    int E, int N,
    const float* __restrict__ X, const __half* __restrict__ WT,
    float* __restrict__ H32, int GB)
{
    __shared__ __half wlds[128][136];
    const int b = blockIdx.x;
    const bool isGemm = ((b % 5) == 0) && (b / 5 < GB);
    if (isGemm) {
        gemm1raw_body(X, WT, H32, N, b / 5, wlds);
        return;
    }
    // fill block id: contiguous over non-gemm blocks
    const int fid = (b < 5 * GB) ? (b - (b / 5 + 1)) : (b - GB);
    int e = fid * 512 + (int)threadIdx.x;
    if (e < E) {
        int d = dst[e], s = src[e];
        int pos = atomicAdd(&cnt[d], 1);
        if (pos < DMAX) {
            csrF[(size_t)d * DMAX + pos] = s;
        } else {
            int o = atomicAdd(&cnt[N], 1);
            ovf[2 * o] = d; ovf[2 * o + 1] = s;
        }
    }
}

// ---------------- scale_k: H16 = fp16( H32 * rsqrt(cnt+1) ) ---------------------
// Single fp16 rounding (fp32 product x fp32 dinv) — numerically identical to
// the fused R7 path; just moved after fill so gemm1 needn't wait on cnt.
__global__ __launch_bounds__(256) void scale_k(
    const float* __restrict__ H32, const int* __restrict__ cnt,
    __half* __restrict__ H16, int n)
{
    int i = blockIdx.x * 256 + threadIdx.x;     // one half8 per thread
    int row = i >> 4, j = i & 15;
    if (row >= n) return;
    float dv = rsqrtf((float)cnt[row] + 1.0f);
    const floatx4* p = (const floatx4*)(H32 + (size_t)row * NF + j * 8);
    floatx4 u = p[0], v = p[1];
    half8 h;
    h[0] = (_Float16)(u[0] * dv); h[1] = (_Float16)(u[1] * dv);
    h[2] = (_Float16)(u[2] * dv); h[3] = (_Float16)(u[3] * dv);
    h[4] = (_Float16)(v[0] * dv); h[5] = (_Float16)(v[1] * dv);
    h[6] = (_Float16)(v[2] * dv); h[7] = (_Float16)(v[3] * dv);
    *(half8*)&H16[(size_t)row * NF + j * 8] = h;
}

// ---------------- gather2w: 2 nodes/wave, 16B/lane loads (R6 champion) ----------
__device__ __forceinline__ void gather2w(
    const half8* __restrict__ hs8, const int* __restrict__ csrF,
    const int* __restrict__ cnt, int nA, int n,
    int g, int fl, int lane, floatx4& ac0, floatx4& ac1,
    const int* __restrict__ ovf, int novf)
{
    const int ep  = g & 1;        // edge parity
    const int isB = g >> 1;       // which node this lane group serves
    const int nB  = nA + 1;

    int cntA = (nA < n) ? cnt[nA] : 0;
    int cntB = (nB < n) ? cnt[nB] : 0;
    const int ccA = min(cntA, DMAX), ccB = min(cntB, DMAX);

    int idxA = (lane < ccA) ? __builtin_nontemporal_load(&csrF[(size_t)nA * DMAX + lane]) : 0;
    int idxB = (lane < ccB) ? __builtin_nontemporal_load(&csrF[(size_t)nB * DMAX + lane]) : 0;

    // self-loops (parity-0 groups only; each group adds its own node's row)
    if (ep == 0) {
        int nd = isB ? nB : nA;
        if (nd < n) {
            half8 s = hs8[(size_t)nd * 16 + fl];
            ac0[0] += (float)s[0]; ac0[1] += (float)s[1];
            ac0[2] += (float)s[2]; ac0[3] += (float)s[3];
            ac1[0] += (float)s[4]; ac1[1] += (float)s[5];
            ac1[2] += (float)s[6]; ac1[3] += (float)s[7];
        }
    }

    const int myc  = isB ? ccB : ccA;
    const int maxc = max(ccA, ccB);
    for (int j = 0; j < maxc; j += 16) {   // 16 edges/node per batch, 8 loads deep
        int s[8];
        half8 v[8];
        #pragma unroll
        for (int t = 0; t < 8; t++) {
            int e = j + 2 * t + ep;
            int eA = min(e, ccA - 1); eA = (eA < 0) ? 0 : eA;
            int eB = min(e, ccB - 1); eB = (eB < 0) ? 0 : eB;
            int sa = __shfl(idxA, eA, 64);
            int sb = __shfl(idxB, eB, 64);
            s[t] = isB ? sb : sa;
        }
        #pragma unroll
        for (int t = 0; t < 8; t++)
            v[t] = hs8[(size_t)s[t] * 16 + fl];
        #pragma unroll
        for (int t = 0; t < 8; t++) {
            if (j + 2 * t + ep < myc) {
                ac0[0] += (float)v[t][0]; ac0[1] += (float)v[t][1];
                ac0[2] += (float)v[t][2]; ac0[3] += (float)v[t][3];
                ac1[0] += (float)v[t][4]; ac1[1] += (float)v[t][5];
                ac1[2] += (float)v[t][6]; ac1[3] += (float)v[t][7];
            }
        }
    }

    // exact-correctness overflow path (deg > DMAX) — empty in practice
    if (novf > 0 && ep == 0) {
        int myN = isB ? nB : nA;
        for (int i = 0; i < novf; i++) {
            int d = ovf[2 * i];
            if (d == myN) {
                half8 v = hs8[(size_t)ovf[2 * i + 1] * 16 + fl];
                ac0[0] += (float)v[0]; ac0[1] += (float)v[1];
                ac0[2] += (float)v[2]; ac0[3] += (float)v[3];
                ac1[0] += (float)v[4]; ac1[1] += (float)v[5];
                ac1[2] += (float)v[6]; ac1[3] += (float)v[7];
            }
        }
    }

    // combine parity halves: xor16 pairs g0<->g1 (node A) and g2<->g3 (node B)
    #pragma unroll
    for (int q = 0; q < 4; q++) {
        ac0[q] += __shfl_xor(ac0[q], 16, 64);
        ac1[q] += __shfl_xor(ac1[q], 16, 64);
    }
}

// ---------------- aggmm: fused agg(layer1) + gemm2; 512 thr, 16 nodes/block -----
__global__ __launch_bounds__(512) void aggmm_k(
    const __half* __restrict__ hs, const int* __restrict__ csrF,
    const int* __restrict__ cnt, const float* __restrict__ bias,
    const __half* __restrict__ WT, __half* __restrict__ Hout, int n,
    const int* __restrict__ ovf)
{
    __shared__ __half alds[16][136];
    const int tid = threadIdx.x;
    const int wave = tid >> 6, lane = tid & 63;
    const int g = lane >> 4, fl = lane & 15;
    const int nb0 = blockIdx.x * 16;
    const int nA = nb0 + wave * 2;
    const int novf = cnt[n];

    floatx4 ac0 = {0.f, 0.f, 0.f, 0.f}, ac1 = {0.f, 0.f, 0.f, 0.f};
    gather2w((const half8*)hs, csrF, cnt, nA, n, g, fl, lane, ac0, ac1, ovf, novf);

    if ((g & 1) == 0) {   // groups 0 (node A) and 2 (node B) write
        int node = nA + (g >> 1);
        int row  = wave * 2 + (g >> 1);
        half8 hv;
        if (node < n) {
            float dv = rsqrtf((float)cnt[node] + 1.0f);
            const floatx4 bv0 = *(const floatx4*)&bias[fl * 8];
            const floatx4 bv1 = *(const floatx4*)&bias[fl * 8 + 4];
            hv[0] = (_Float16)fmaxf(dv * ac0[0] + bv0[0], 0.f);
            hv[1] = (_Float16)fmaxf(dv * ac0[1] + bv0[1], 0.f);
            hv[2] = (_Float16)fmaxf(dv * ac0[2] + bv0[2], 0.f);
            hv[3] = (_Float16)fmaxf(dv * ac0[3] + bv0[3], 0.f);
            hv[4] = (_Float16)fmaxf(dv * ac1[0] + bv1[0], 0.f);
            hv[5] = (_Float16)fmaxf(dv * ac1[1] + bv1[1], 0.f);
            hv[6] = (_Float16)fmaxf(dv * ac1[2] + bv1[2], 0.f);
            hv[7] = (_Float16)fmaxf(dv * ac1[3] + bv1[3], 0.f);
        } else {
            #pragma unroll
            for (int i = 0; i < 8; i++) hv[i] = (_Float16)0.f;
        }
        *(half8*)&alds[row][fl * 8] = hv;
    }
    __syncthreads();

    // 16x128 output tile: wave w owns col-tile ct = w (16 cols)
    const int quad = lane >> 4, l15 = lane & 15;
    const int ct = wave;
    half8 afr[4];
    #pragma unroll
    for (int kc = 0; kc < 4; kc++)
        afr[kc] = *(const half8*)&alds[l15][kc * 32 + quad * 8];

    floatx4 o0 = {0.f, 0.f, 0.f, 0.f};
    #pragma unroll
    for (int kc = 0; kc < 4; kc++) {
        half8 b = *(const half8*)(WT + (size_t)(ct * 16 + l15) * NF + kc * 32 + quad * 8);
        o0 = __builtin_amdgcn_mfma_f32_16x16x32_f16(afr[kc], b, o0, 0, 0, 0);
    }

    #pragma unroll
    for (int r = 0; r < 4; r++) {
        int node = nb0 + quad * 4 + r;
        if (node < n) {
            float dv = rsqrtf((float)cnt[node] + 1.0f);
            Hout[(size_t)node * NF + ct * 16 + l15] = __float2half(o0[r] * dv);
        }
    }
}

// ---------------- agg4: final aggregate (fp32 out); 256 thr, 8 nodes/block ------
__global__ __launch_bounds__(256) void agg4_k(
    const __half* __restrict__ hs, const int* __restrict__ csrF,
    const int* __restrict__ cnt, const float* __restrict__ bias,
    float* __restrict__ outf, int n, const int* __restrict__ ovf)
{
    const int tid = threadIdx.x;
    const int wave = tid >> 6, lane = tid & 63;
    const int g = lane >> 4, fl = lane & 15;
    const int nA = blockIdx.x * 8 + wave * 2;
    if (nA >= n) return;
    const int novf = cnt[n];

    floatx4 ac0 = {0.f, 0.f, 0.f, 0.f}, ac1 = {0.f, 0.f, 0.f, 0.f};
    gather2w((const half8*)hs, csrF, cnt, nA, n, g, fl, lane, ac0, ac1, ovf, novf);

    if ((g & 1) == 0) {
        int node = nA + (g >> 1);
        if (node < n) {
            float dv = rsqrtf((float)cnt[node] + 1.0f);
            const floatx4 bv0 = *(const floatx4*)&bias[fl * 8];
            const floatx4 bv1 = *(const floatx4*)&bias[fl * 8 + 4];
            floatx4 w0, w1;
            w0[0] = dv * ac0[0] + bv0[0]; w0[1] = dv * ac0[1] + bv0[1];
            w0[2] = dv * ac0[2] + bv0[2]; w0[3] = dv * ac0[3] + bv0[3];
            w1[0] = dv * ac1[0] + bv1[0]; w1[1] = dv * ac1[1] + bv1[1];
            w1[2] = dv * ac1[2] + bv1[2]; w1[3] = dv * ac1[3] + bv1[3];
            *(floatx4*)(outf + (size_t)node * NF + fl * 8)     = w0;
            *(floatx4*)(outf + (size_t)node * NF + fl * 8 + 4) = w1;
        }
    }
}

// ---------------- launch ----------------

extern "C" void kernel_launch(void* const* d_in, const int* in_sizes, int n_in,
                              void* d_out, int out_size, void* d_ws, size_t ws_size,
                              hipStream_t stream) {
    const float* x  = (const float*)d_in[0];
    const int*   ei = (const int*)d_in[1];
    const float* W1 = (const float*)d_in[2];
    const float* b1 = (const float*)d_in[3];
    const float* W2 = (const float*)d_in[4];
    const float* b2 = (const float*)d_in[5];
    float* out = (float*)d_out;

    const int N = in_sizes[0] / NF;   // 50000
    const int E = in_sizes[1] / 2;    // 800000
    const int* src = ei;
    const int* dst = ei + E;

    char* ws = (char*)d_ws;
    size_t off = 0;
    auto alloc = [&](size_t bytes) {
        void* p = ws + off;
        off += bytes;
        off = (off + 63) & ~(size_t)63;
        return p;
    };
    int*    cnt  = (int*)alloc((size_t)(N + 1) * 4);        // degrees + ovf ctr
    int*    csrF = (int*)alloc((size_t)N * DMAX * 4);       // fixed-stride CSR
    int*    ovf  = (int*)alloc((size_t)E * 2 * 4);          // exact overflow list
    float*  H32  = (float*)alloc((size_t)N * NF * 4);       // unscaled gemm1 out
    __half* WT1  = (__half*)alloc((size_t)NF * NF * 2);
    __half* WT2  = (__half*)alloc((size_t)NF * NF * 2);
    __half* H16  = (__half*)alloc((size_t)N * NF * 2);
    __half* A16  = (__half*)alloc((size_t)N * NF * 2);

    int zb  = (N + 1 + 255) / 256;         // zero-blocks
    int GB  = (N + 127) / 128;             // gemm1 blocks (512 thr)
    int fb  = (E + 511) / 512;             // fill blocks (1 edge/thread)
    int sb  = (N * 16 + 255) / 256;        // scale blocks
    int mb  = (N + 15) / 16;               // aggmm blocks (16 nodes, 512 thr)
    int ab  = (N + 7) / 8;                 // agg4 blocks (8 nodes, 256 thr)

    // zero degree counters + transpose W1/W2 to fp16
    z_k<<<zb + 128, 256, 0, stream>>>(cnt, N, zb, W1, W2, WT1, WT2);
    // co-dispatched CSR fill + unscaled gemm1 (independent; 1:4 interleave)
    mix_k<<<fb + GB, 512, 0, stream>>>(src, dst, cnt, csrF, ovf, E, N,
                                       x, WT1, H32, GB);
    // apply dinv scaling (single fp16 rounding, same numerics as before)
    scale_k<<<sb, 256, 0, stream>>>(H32, cnt, H16, N);
    // fused layer-1 aggregate + layer-2 GEMM
    aggmm_k<<<mb, 512, 0, stream>>>(H16, csrF, cnt, b1, WT2, A16, N, ovf);
    // final aggregate -> fp32 output
    agg4_k<<<ab, 256, 0, stream>>>(A16, csrF, cnt, b2, out, N, ovf);
}